// Round 7
// baseline (109.082 us; speedup 1.0000x reference)
//
#include <hip/hip_runtime.h>
#include <hip/hip_bf16.h>

typedef __attribute__((ext_vector_type(8))) short bf16x8;
typedef __attribute__((ext_vector_type(4))) float f32x4;

#define CIN   128
#define HW    64
#define OUTC  256

#define BP_OFF     33554432ULL
#define ZP_OFF     34144256ULL
#define WS_NEEDED  34148352ULL

#define SB  __builtin_amdgcn_s_barrier()
#define SCB __builtin_amdgcn_sched_barrier(0)
#define WAITV(N) asm volatile("s_waitcnt vmcnt(" #N ")" ::: "memory")
#define MFMA(a, b, c) __builtin_amdgcn_mfma_f32_16x16x32_bf16(a, b, c, 0, 0, 0)

// ============ fused prep: Xt transpose + Bp transpose + zp zero ============
__global__ __launch_bounds__(256) void conv_prep(const float* __restrict__ X,
                                                 const float* __restrict__ Kw,
                                                 __hip_bfloat16* __restrict__ Xt,
                                                 __hip_bfloat16* __restrict__ Bp,
                                                 __hip_bfloat16* __restrict__ zp) {
    const int blk = blockIdx.x;
    if (blk < 2048) {
        // X (b,c,y,x) f32 -> Xt (b,y,x,c) bf16
        __shared__ __hip_bfloat16 L[64][136];
        const int b = blk >> 6;
        const int y = blk & 63;
        const int x = threadIdx.x & 63;
        const int c0 = (threadIdx.x >> 6) * 32;
        const float* src = X + (((long)(b * CIN + c0) * HW + y) * HW + x);
        #pragma unroll
        for (int j = 0; j < 32; j += 2) {
            float v0 = src[(long)j * (HW * HW)];
            float v1 = src[(long)(j + 1) * (HW * HW)];
            __hip_bfloat162 p;
            p.x = __float2bfloat16(v0);
            p.y = __float2bfloat16(v1);
            *reinterpret_cast<__hip_bfloat162*>(&L[x][c0 + j]) = p;
        }
        __syncthreads();
        __hip_bfloat16* dst = Xt + (long)blk * (64 * 128);
        #pragma unroll
        for (int it = 0; it < 4; ++it) {
            int G = it * 256 + threadIdx.x;
            int xx = G >> 4, g = G & 15;
            bf16x8 v = *reinterpret_cast<const bf16x8*>(&L[xx][g * 8]);
            *reinterpret_cast<bf16x8*>(&dst[(long)G * 8]) = v;
        }
    } else if (blk < 2112) {
        // Kw (k=c*9+ij, n) f32 -> Bp (ij,n,c) bf16
        for (int idx = (blk - 2048) * 256 + threadIdx.x; idx < 294912; idx += 64 * 256) {
            int c  = idx & 127;
            int n  = (idx >> 7) & 255;
            int ij = idx >> 15;
            Bp[idx] = __float2bfloat16(Kw[((c * 9 + ij) << 8) + n]);
        }
    } else {
        *reinterpret_cast<float4*>((char*)zp + threadIdx.x * 16) = float4{0.f, 0.f, 0.f, 0.f};
    }
}

// ================= implicit GEMM: 36 half-tile phases, 4-deep ring =================
// M=131072, N=256, K=1152 = 36 halves of 32 (half H: ij=H>>2, c0=(H&3)*32)
// BM=256 (4 y-rows), BN=256, 8 waves 2Mx4N, per-wave 128x64
// LDS: As/Bs [ring=H&3][256*32] = 128 KiB total
// Phase: [12 ds_read ; 4 stage ; vmcnt(8) ; SB ; 32 MFMA ; SB]
__global__ __launch_bounds__(512, 2) void conv_igemm6(
    const __hip_bfloat16* __restrict__ Xt,
    const __hip_bfloat16* __restrict__ Bp,
    const __hip_bfloat16* __restrict__ zp,
    float* __restrict__ out)
{
    __shared__ __hip_bfloat16 As[4][256 * 32];
    __shared__ __hip_bfloat16 Bs[4][256 * 32];

    const int tid  = threadIdx.x;
    const int wv   = tid >> 6;
    const int lane = tid & 63;
    const int l16  = lane & 15;
    const int d16  = lane >> 4;
    const int wr   = wv >> 2;        // m-offset 128*wr
    const int wc   = wv & 3;         // n-offset 64*wc

    // XCD-chunked bijective swizzle (512 % 8 == 0)
    const int bid   = blockIdx.x;
    const int mtile = (bid & 7) * 64 + (bid >> 3);
    const int b  = mtile >> 4;
    const int y0 = (mtile & 15) * 4;

    const int srow = lane >> 2;      // 0..15
    const int sg   = lane & 3;       // LDS granule slot 0..3

    f32x4 acc[8][4] = {};

    // hoisted per-lane staging bases; swizzle: slot s of row r holds G=(s-(r>>1))&3
    const int r0  = wv * 32 + srow;
    const int r1  = r0 + 16;
    const int G0  = (sg - (r0 >> 1)) & 3;
    const int G1  = (sg - (r1 >> 1)) & 3;
    const int xr0 = r0 & 63, xr1 = r1 & 63;
    const int yy0 = y0 + (r0 >> 6), yy1 = y0 + (r1 >> 6);
    const __hip_bfloat16* pA0 = Xt + (((long)b * 4096 + yy0 * 64 + xr0) * 128 + G0 * 8);
    const __hip_bfloat16* pA1 = Xt + (((long)b * 4096 + yy1 * 64 + xr1) * 128 + G1 * 8);
    const __hip_bfloat16* pB0 = Bp + ((long)r0 * 128 + G0 * 8);
    const __hip_bfloat16* pB1 = Bp + ((long)r1 * 128 + G1 * 8);
    const int ldsOff0 = (wv * 32) * 32;        // bf16 elements
    const int ldsOff1 = (wv * 32 + 16) * 32;

    // stage half S (S literal after unroll): ij=S>>2, c0=(S&3)*32, ring buf S&3
    auto stage = [&](int S) {
        const int ij = S >> 2;
        const int c0 = (S & 3) * 32;
        const int di = ij / 3 - 1;
        const int dj = ij % 3 - 1;
        const long offA = (long)(di * 64 + dj) * 128 + c0;
        const bool ok0 = ((unsigned)(xr0 + dj) < 64u) && ((unsigned)(yy0 + di) < 64u);
        const bool ok1 = ((unsigned)(xr1 + dj) < 64u) && ((unsigned)(yy1 + di) < 64u);
        const __hip_bfloat16* gA0 = ok0 ? pA0 + offA : zp + c0;
        const __hip_bfloat16* gA1 = ok1 ? pA1 + offA : zp + c0;
        __hip_bfloat16* ldsA = &As[S & 3][0];
        __builtin_amdgcn_global_load_lds(
            (const __attribute__((address_space(1))) void*)gA0,
            (__attribute__((address_space(3))) void*)(ldsA + ldsOff0), 16, 0, 0);
        __builtin_amdgcn_global_load_lds(
            (const __attribute__((address_space(1))) void*)gA1,
            (__attribute__((address_space(3))) void*)(ldsA + ldsOff1), 16, 0, 0);
        const long offB = (long)ij * 32768 + c0;
        __hip_bfloat16* ldsB = &Bs[S & 3][0];
        __builtin_amdgcn_global_load_lds(
            (const __attribute__((address_space(1))) void*)(pB0 + offB),
            (__attribute__((address_space(3))) void*)(ldsB + ldsOff0), 16, 0, 0);
        __builtin_amdgcn_global_load_lds(
            (const __attribute__((address_space(1))) void*)(pB1 + offB),
            (__attribute__((address_space(3))) void*)(ldsB + ldsOff1), 16, 0, 0);
    };

    // prologue: stage halves 0,1,2 (12 loads); ensure half 0 landed
    stage(0); stage(1); stage(2);
    WAITV(8);
    SCB; SB;

    #pragma unroll
    for (int H = 0; H < 36; ++H) {
        const int RB = H & 3;
        // ---- 12 ds_read_b128 for this half (pre-barrier; latency hides) ----
        bf16x8 Af[8], Bf[4];
        #pragma unroll
        for (int mi = 0; mi < 8; ++mi) {
            const int m = wr * 128 + mi * 16 + l16;
            const int s = (d16 + (m >> 1)) & 3;
            Af[mi] = *reinterpret_cast<const bf16x8*>(&As[RB][m * 32 + s * 8]);
        }
        #pragma unroll
        for (int ni = 0; ni < 4; ++ni) {
            const int n = wc * 64 + ni * 16 + l16;
            const int s = (d16 + (n >> 1)) & 3;
            Bf[ni] = *reinterpret_cast<const bf16x8*>(&Bs[RB][n * 32 + s * 8]);
        }
        // ---- stage half H+3 (overwrites ring slot consumed in phase H-1) ----
        if (H < 33) stage(H + 3);
        // ---- counted vmcnt: my stage from 3 phases ago must have landed ----
        if (H < 33)       WAITV(8);
        else if (H == 33) WAITV(4);
        else if (H == 34) WAITV(0);
        SCB; SB;
        // ---- 32 MFMA (compiler inserts fine-grained lgkmcnt) ----
        __builtin_amdgcn_s_setprio(1);
        #pragma unroll
        for (int ni = 0; ni < 4; ++ni)
            #pragma unroll
            for (int mi = 0; mi < 8; ++mi)
                acc[mi][ni] = MFMA(Af[mi], Bf[ni], acc[mi][ni]);
        __builtin_amdgcn_s_setprio(0);
        SCB; SB;
    }

    // ---- epilogue: float4 stores; zero y==63 / x==63 ----
    #pragma unroll
    for (int mi = 0; mi < 8; ++mi) {
        const int m  = wr * 128 + mi * 16 + d16 * 4;
        const int x0 = m & 63;
        const int y  = y0 + (m >> 6);
        #pragma unroll
        for (int ni = 0; ni < 4; ++ni) {
            const int o = wc * 64 + ni * 16 + l16;
            float4 v;
            v.x = acc[mi][ni][0];
            v.y = acc[mi][ni][1];
            v.z = acc[mi][ni][2];
            v.w = acc[mi][ni][3];
            if (y == HW - 1) { v.x = v.y = v.z = v.w = 0.f; }
            if (x0 + 3 == HW - 1) v.w = 0.f;
            *reinterpret_cast<float4*>(
                out + ((long)(b * OUTC + o) * 4096 + y * 64 + x0)) = v;
        }
    }
}

// ================= fallback (round-1 kernel) if ws too small =================
__global__ __launch_bounds__(256) void conv_igemm_bf16(
    const float* __restrict__ X, const float* __restrict__ Kw, float* __restrict__ out) {
    __shared__ __hip_bfloat16 As[128][40];
    __shared__ __hip_bfloat16 Bs[128][40];
    const int tid = threadIdx.x, wave = tid >> 6, lane = tid & 63;
    const int l16 = lane & 15, d16 = lane >> 4;
    const int m_base = blockIdx.x * 128;
    const int b = m_base >> 12, y0 = (m_base & 4095) >> 6;
    const int n_base = blockIdx.y * 128;
    const int wm = (wave >> 1) * 64, wn = (wave & 1) * 64;
    f32x4 acc[4][4] = {};
    const int smm = tid & 127, ccb = tid >> 7;
    const int sx = smm & 63, syr = smm >> 6;
    for (int ij = 0; ij < 9; ++ij) {
        const int di = ij / 3 - 1, dj = ij % 3 - 1;
        const int xp = sx + dj, yp = y0 + syr + di;
        const bool ok = ((unsigned)xp < 64u) && ((unsigned)yp < 64u);
        const long xbase = (((long)b * CIN) * HW + yp) * HW + xp;
        for (int c0 = 0; c0 < CIN; c0 += 32) {
            for (int cc = ccb; cc < 32; cc += 2) {
                float v = ok ? X[xbase + (long)(c0 + cc) * 4096] : 0.f;
                As[smm][cc] = __float2bfloat16(v);
                Bs[smm][cc] = __float2bfloat16(Kw[((c0 + cc) * 9 + ij) * OUTC + n_base + smm]);
            }
            __syncthreads();
            bf16x8 afrag[4], bfrag[4];
            for (int mi = 0; mi < 4; ++mi)
                afrag[mi] = *reinterpret_cast<const bf16x8*>(&As[wm + mi * 16 + l16][d16 * 8]);
            for (int ni = 0; ni < 4; ++ni)
                bfrag[ni] = *reinterpret_cast<const bf16x8*>(&Bs[wn + ni * 16 + l16][d16 * 8]);
            for (int mi = 0; mi < 4; ++mi)
                for (int ni = 0; ni < 4; ++ni)
                    acc[mi][ni] = __builtin_amdgcn_mfma_f32_16x16x32_bf16(
                        afrag[mi], bfrag[ni], acc[mi][ni], 0, 0, 0);
            __syncthreads();
        }
    }
    for (int mi = 0; mi < 4; ++mi)
        for (int ni = 0; ni < 4; ++ni)
            for (int r = 0; r < 4; ++r) {
                const int mm = wm + mi * 16 + d16 * 4 + r;
                const int nn = wn + ni * 16 + l16;
                const int y = y0 + (mm >> 6), x = mm & 63, o = n_base + nn;
                float v = acc[mi][ni][r];
                if (y == 63 || x == 63) v = 0.f;
                out[(((long)b * OUTC + o) * HW + y) * HW + x] = v;
            }
}

extern "C" void kernel_launch(void* const* d_in, const int* in_sizes, int n_in,
                              void* d_out, int out_size, void* d_ws, size_t ws_size,
                              hipStream_t stream) {
    const float* X  = (const float*)d_in[0];
    const float* Kw = (const float*)d_in[1];
    float* out = (float*)d_out;

    if (ws_size >= WS_NEEDED) {
        char* ws = (char*)d_ws;
        __hip_bfloat16* Xt = (__hip_bfloat16*)ws;
        __hip_bfloat16* Bp = (__hip_bfloat16*)(ws + BP_OFF);
        __hip_bfloat16* zp = (__hip_bfloat16*)(ws + ZP_OFF);
        conv_prep<<<dim3(2113), dim3(256), 0, stream>>>(X, Kw, Xt, Bp, zp);
        conv_igemm6<<<dim3(512), dim3(512), 0, stream>>>(Xt, Bp, zp, out);
    } else {
        conv_igemm_bf16<<<dim3(1024, 2), dim3(256), 0, stream>>>(X, Kw, out);
    }
}

// Round 8
// 105.328 us; speedup vs baseline: 1.0356x; 1.0356x over previous
//
#include <hip/hip_runtime.h>
#include <hip/hip_bf16.h>

typedef __attribute__((ext_vector_type(8))) short bf16x8;
typedef __attribute__((ext_vector_type(4))) float f32x4;

#define CIN   128
#define HW    64
#define OUTC  256

#define BP_OFF     33554432ULL
#define ZP_OFF     34144256ULL
#define WS_NEEDED  34148352ULL

#define SB  __builtin_amdgcn_s_barrier()
#define SCB __builtin_amdgcn_sched_barrier(0)
#define WAITV(N) asm volatile("s_waitcnt vmcnt(" #N ")" ::: "memory")
#define MFMA(a, b, c) __builtin_amdgcn_mfma_f32_16x16x32_bf16(a, b, c, 0, 0, 0)

// ============ fused prep ============
// Xt2: bf16 [32][4][64][64][32]  (b, cc=c>>5, y, x, c&31) — staging-contiguous
// Bp2: bf16 [9][4][256][32]      (ij, cc, n, c&31)
__global__ __launch_bounds__(256) void conv_prep(const float* __restrict__ X,
                                                 const float* __restrict__ Kw,
                                                 __hip_bfloat16* __restrict__ Xt2,
                                                 __hip_bfloat16* __restrict__ Bp2,
                                                 __hip_bfloat16* __restrict__ zp) {
    const int blk = blockIdx.x;
    if (blk < 2048) {
        // X (b,c,y,x) f32 -> Xt2 (b,cc,y,x,c32) bf16
        __shared__ __hip_bfloat16 L[64][136];
        const int b = blk >> 6;
        const int y = blk & 63;
        const int x = threadIdx.x & 63;
        const int c0 = (threadIdx.x >> 6) * 32;
        const float* src = X + (((long)(b * CIN + c0) * HW + y) * HW + x);
        #pragma unroll
        for (int j = 0; j < 32; j += 2) {
            float v0 = src[(long)j * (HW * HW)];
            float v1 = src[(long)(j + 1) * (HW * HW)];
            __hip_bfloat162 p;
            p.x = __float2bfloat16(v0);
            p.y = __float2bfloat16(v1);
            *reinterpret_cast<__hip_bfloat162*>(&L[x][c0 + j]) = p;
        }
        __syncthreads();
        // write 4 cc-chunks; per cc: 64 x * 32 c = 4 KiB = 256 threads * 16 B
        const int xx = threadIdx.x >> 2;
        const int g  = threadIdx.x & 3;
        #pragma unroll
        for (int cc = 0; cc < 4; ++cc) {
            bf16x8 v = *reinterpret_cast<const bf16x8*>(&L[xx][cc * 32 + g * 8]);
            long dst = (((long)(b * 4 + cc) * 64 + y) * 64 + xx) * 32 + g * 8;
            *reinterpret_cast<bf16x8*>(&Xt2[dst]) = v;
        }
    } else if (blk < 2112) {
        // Kw (k=c*9+ij, n) f32 -> Bp2 (ij,cc,n,c32) bf16
        for (int i = (blk - 2048) * 256 + threadIdx.x; i < 294912; i += 64 * 256) {
            int c32 = i & 31;
            int n   = (i >> 5) & 255;
            int cc  = (i >> 13) & 3;
            int ij  = i >> 15;
            int c   = cc * 32 + c32;
            Bp2[i] = __float2bfloat16(Kw[(c * 9 + ij) * 256 + n]);
        }
    } else {
        *reinterpret_cast<float4*>((char*)zp + threadIdx.x * 16) = float4{0.f, 0.f, 0.f, 0.f};
    }
}

// ================= implicit GEMM: 36 half-tile phases, 4-deep ring =================
// identical schedule to R7; only staging-source addressing changed (contiguous 1 KiB)
__global__ __launch_bounds__(512, 2) void conv_igemm7(
    const __hip_bfloat16* __restrict__ Xt2,
    const __hip_bfloat16* __restrict__ Bp2,
    const __hip_bfloat16* __restrict__ zp,
    float* __restrict__ out)
{
    __shared__ __hip_bfloat16 As[4][256 * 32];
    __shared__ __hip_bfloat16 Bs[4][256 * 32];

    const int tid  = threadIdx.x;
    const int wv   = tid >> 6;
    const int lane = tid & 63;
    const int l16  = lane & 15;
    const int d16  = lane >> 4;
    const int wr   = wv >> 2;        // m-offset 128*wr
    const int wc   = wv & 3;         // n-offset 64*wc

    // XCD-chunked bijective swizzle (512 % 8 == 0)
    const int bid   = blockIdx.x;
    const int mtile = (bid & 7) * 64 + (bid >> 3);
    const int b  = mtile >> 4;
    const int y0 = (mtile & 15) * 4;

    const int srow = lane >> 2;      // 0..15
    const int sg   = lane & 3;       // LDS granule slot 0..3

    f32x4 acc[8][4] = {};

    // per-lane staging bases; swizzle: slot s of row r holds source granule (s-(r>>1))&3
    const int r0  = wv * 32 + srow;
    const int r1  = r0 + 16;
    const int G0  = (sg - (r0 >> 1)) & 3;
    const int G1  = (sg - (r1 >> 1)) & 3;
    const int xr0 = r0 & 63, xr1 = r1 & 63;
    const int yy0 = y0 + (r0 >> 6), yy1 = y0 + (r1 >> 6);
    // Xt2 element index: ((b*4+cc)*64 + y)*64*32 + x*32 + c32  (cc added per-phase)
    const __hip_bfloat16* pA0 = Xt2 + (((long)b * 16384 + yy0 * 64 + xr0) * 32 + G0 * 8);
    const __hip_bfloat16* pA1 = Xt2 + (((long)b * 16384 + yy1 * 64 + xr1) * 32 + G1 * 8);
    // Bp2 element index: (ij*4+cc)*8192 + n*32 + c32
    const __hip_bfloat16* pB0 = Bp2 + ((long)r0 * 32 + G0 * 8);
    const __hip_bfloat16* pB1 = Bp2 + ((long)r1 * 32 + G1 * 8);
    const __hip_bfloat16* zp0 = zp + G0 * 8;
    const __hip_bfloat16* zp1 = zp + G1 * 8;
    const int ldsOff0 = (wv * 32) * 32;        // bf16 elements
    const int ldsOff1 = (wv * 32 + 16) * 32;

    // stage half S: ij=S>>2, cc=S&3, ring buf S&3. 4 contiguous 1-KiB loads/wave.
    auto stage = [&](int S) {
        const int ij = S >> 2;
        const int cc = S & 3;
        const int di = ij / 3 - 1;
        const int dj = ij % 3 - 1;
        const long offA = ((long)cc * 4096 + di * 64 + dj) * 32;
        const bool ok0 = ((unsigned)(xr0 + dj) < 64u) && ((unsigned)(yy0 + di) < 64u);
        const bool ok1 = ((unsigned)(xr1 + dj) < 64u) && ((unsigned)(yy1 + di) < 64u);
        const __hip_bfloat16* gA0 = ok0 ? pA0 + offA : zp0;
        const __hip_bfloat16* gA1 = ok1 ? pA1 + offA : zp1;
        __hip_bfloat16* ldsA = &As[S & 3][0];
        __builtin_amdgcn_global_load_lds(
            (const __attribute__((address_space(1))) void*)gA0,
            (__attribute__((address_space(3))) void*)(ldsA + ldsOff0), 16, 0, 0);
        __builtin_amdgcn_global_load_lds(
            (const __attribute__((address_space(1))) void*)gA1,
            (__attribute__((address_space(3))) void*)(ldsA + ldsOff1), 16, 0, 0);
        const long offB = (long)(ij * 4 + cc) * 8192;
        __hip_bfloat16* ldsB = &Bs[S & 3][0];
        __builtin_amdgcn_global_load_lds(
            (const __attribute__((address_space(1))) void*)(pB0 + offB),
            (__attribute__((address_space(3))) void*)(ldsB + ldsOff0), 16, 0, 0);
        __builtin_amdgcn_global_load_lds(
            (const __attribute__((address_space(1))) void*)(pB1 + offB),
            (__attribute__((address_space(3))) void*)(ldsB + ldsOff1), 16, 0, 0);
    };

    // prologue: stage halves 0,1,2 (12 loads); ensure half 0 landed
    stage(0); stage(1); stage(2);
    WAITV(8);
    SCB; SB;

    #pragma unroll
    for (int H = 0; H < 36; ++H) {
        const int RB = H & 3;
        // ---- 12 ds_read_b128 (pre-barrier; latency hides) ----
        bf16x8 Af[8], Bf[4];
        #pragma unroll
        for (int mi = 0; mi < 8; ++mi) {
            const int m = wr * 128 + mi * 16 + l16;
            const int s = (d16 + (m >> 1)) & 3;
            Af[mi] = *reinterpret_cast<const bf16x8*>(&As[RB][m * 32 + s * 8]);
        }
        #pragma unroll
        for (int ni = 0; ni < 4; ++ni) {
            const int n = wc * 64 + ni * 16 + l16;
            const int s = (d16 + (n >> 1)) & 3;
            Bf[ni] = *reinterpret_cast<const bf16x8*>(&Bs[RB][n * 32 + s * 8]);
        }
        // ---- stage half H+3 (overwrites ring slot consumed in phase H-1) ----
        if (H < 33) stage(H + 3);
        // ---- counted vmcnt: half H+1 must have landed ----
        if (H < 33)       WAITV(8);
        else if (H == 33) WAITV(4);
        else if (H == 34) WAITV(0);
        SCB; SB;
        // ---- 32 MFMA (compiler inserts fine-grained lgkmcnt) ----
        __builtin_amdgcn_s_setprio(1);
        #pragma unroll
        for (int ni = 0; ni < 4; ++ni)
            #pragma unroll
            for (int mi = 0; mi < 8; ++mi)
                acc[mi][ni] = MFMA(Af[mi], Bf[ni], acc[mi][ni]);
        __builtin_amdgcn_s_setprio(0);
        SCB; SB;
    }

    // ---- epilogue: float4 stores; zero y==63 / x==63 ----
    #pragma unroll
    for (int mi = 0; mi < 8; ++mi) {
        const int m  = wr * 128 + mi * 16 + d16 * 4;
        const int x0 = m & 63;
        const int y  = y0 + (m >> 6);
        #pragma unroll
        for (int ni = 0; ni < 4; ++ni) {
            const int o = wc * 64 + ni * 16 + l16;
            float4 v;
            v.x = acc[mi][ni][0];
            v.y = acc[mi][ni][1];
            v.z = acc[mi][ni][2];
            v.w = acc[mi][ni][3];
            if (y == HW - 1) { v.x = v.y = v.z = v.w = 0.f; }
            if (x0 + 3 == HW - 1) v.w = 0.f;
            *reinterpret_cast<float4*>(
                out + ((long)(b * OUTC + o) * 4096 + y * 64 + x0)) = v;
        }
    }
}

// ================= fallback (round-1 kernel) if ws too small =================
__global__ __launch_bounds__(256) void conv_igemm_bf16(
    const float* __restrict__ X, const float* __restrict__ Kw, float* __restrict__ out) {
    __shared__ __hip_bfloat16 As[128][40];
    __shared__ __hip_bfloat16 Bs[128][40];
    const int tid = threadIdx.x, wave = tid >> 6, lane = tid & 63;
    const int l16 = lane & 15, d16 = lane >> 4;
    const int m_base = blockIdx.x * 128;
    const int b = m_base >> 12, y0 = (m_base & 4095) >> 6;
    const int n_base = blockIdx.y * 128;
    const int wm = (wave >> 1) * 64, wn = (wave & 1) * 64;
    f32x4 acc[4][4] = {};
    const int smm = tid & 127, ccb = tid >> 7;
    const int sx = smm & 63, syr = smm >> 6;
    for (int ij = 0; ij < 9; ++ij) {
        const int di = ij / 3 - 1, dj = ij % 3 - 1;
        const int xp = sx + dj, yp = y0 + syr + di;
        const bool ok = ((unsigned)xp < 64u) && ((unsigned)yp < 64u);
        const long xbase = (((long)b * CIN) * HW + yp) * HW + xp;
        for (int c0 = 0; c0 < CIN; c0 += 32) {
            for (int cc = ccb; cc < 32; cc += 2) {
                float v = ok ? X[xbase + (long)(c0 + cc) * 4096] : 0.f;
                As[smm][cc] = __float2bfloat16(v);
                Bs[smm][cc] = __float2bfloat16(Kw[((c0 + cc) * 9 + ij) * OUTC + n_base + smm]);
            }
            __syncthreads();
            bf16x8 afrag[4], bfrag[4];
            for (int mi = 0; mi < 4; ++mi)
                afrag[mi] = *reinterpret_cast<const bf16x8*>(&As[wm + mi * 16 + l16][d16 * 8]);
            for (int ni = 0; ni < 4; ++ni)
                bfrag[ni] = *reinterpret_cast<const bf16x8*>(&Bs[wn + ni * 16 + l16][d16 * 8]);
            for (int mi = 0; mi < 4; ++mi)
                for (int ni = 0; ni < 4; ++ni)
                    acc[mi][ni] = __builtin_amdgcn_mfma_f32_16x16x32_bf16(
                        afrag[mi], bfrag[ni], acc[mi][ni], 0, 0, 0);
            __syncthreads();
        }
    }
    for (int mi = 0; mi < 4; ++mi)
        for (int ni = 0; ni < 4; ++ni)
            for (int r = 0; r < 4; ++r) {
                const int mm = wm + mi * 16 + d16 * 4 + r;
                const int nn = wn + ni * 16 + l16;
                const int y = y0 + (mm >> 6), x = mm & 63, o = n_base + nn;
                float v = acc[mi][ni][r];
                if (y == 63 || x == 63) v = 0.f;
                out[(((long)b * OUTC + o) * HW + y) * HW + x] = v;
            }
}

extern "C" void kernel_launch(void* const* d_in, const int* in_sizes, int n_in,
                              void* d_out, int out_size, void* d_ws, size_t ws_size,
                              hipStream_t stream) {
    const float* X  = (const float*)d_in[0];
    const float* Kw = (const float*)d_in[1];
    float* out = (float*)d_out;

    if (ws_size >= WS_NEEDED) {
        char* ws = (char*)d_ws;
        __hip_bfloat16* Xt2 = (__hip_bfloat16*)ws;
        __hip_bfloat16* Bp2 = (__hip_bfloat16*)(ws + BP_OFF);
        __hip_bfloat16* zp  = (__hip_bfloat16*)(ws + ZP_OFF);
        conv_prep<<<dim3(2113), dim3(256), 0, stream>>>(X, Kw, Xt2, Bp2, zp);
        conv_igemm7<<<dim3(512), dim3(512), 0, stream>>>(Xt2, Bp2, zp, out);
    } else {
        conv_igemm_bf16<<<dim3(1024, 2), dim3(256), 0, stream>>>(X, Kw, out);
    }
}